// Round 26
// baseline (125.626 us; speedup 1.0000x reference)
//
#include <hip/hip_runtime.h>
#include <hip/hip_fp16.h>
#include <hip/hip_fp8.h>
#include <math.h>

#define N_NODES 50000
#define N_EDGES 800000
#define N_FEAT 100
#define N_CLASSES 40
#define ROWB 64                    // fp8 row stride: 40 data + 24 pad = 1 cache line
#define N_SLICES 8
#define SLICE_NODES 6250           // N_NODES / N_SLICES
#define N_CHUNKS 125
#define EPC 6400                   // N_EDGES / N_CHUNKS
#define CF_BLOCKS (N_SLICES * N_CHUNKS)  // 1000
#define SCAN_BLK 256
#define N_SCAN_BLKS 196
#define PAD 8                      // csr segment padding granularity (zero entries)
// front grid-union: [0,1000) count | then 16-supers of 8 convert + 5 linear + 3 csr-zero
#define CONV_UNITS 3125
#define LIN_UNITS 1954
#define ZERO_UNITS 1173            // x256 uint4 = 1,201,152 entries >= max padded csr
#define N_SUPER 391
#define FRONT_BLOCKS (CF_BLOCKS + N_SUPER * 16)  // 1000 + 6256
#define CSR_ALLOC_ENTRIES (ZERO_UNITS * 256 * 4)  // 1,201,152

// ---------------- fp8 e4m3 helpers ----------------

__device__ __forceinline__ unsigned char f2q(float x) {
    __hip_fp8_e4m3 q(x);
    return (unsigned char)q.__x;
}
#if __has_builtin(__builtin_amdgcn_cvt_f32_fp8)
__device__ __forceinline__ float q2f(unsigned int b) {
    return __builtin_amdgcn_cvt_f32_fp8((int)b, 0);
}
#else
__device__ __forceinline__ float q2f(unsigned int b) {
    __hip_fp8_e4m3 q;
    q.__x = (__hip_fp8_storage_t)(b & 0xffu);
    return (float)q;
}
#endif

// ---------------- front grid-union: count | convert | linear | csr-zero ----------------
// count reads dest cols from ei with the SAME guarded dtype logic as convert:
// detect on row half (always in-bounds for int32 AND int64 buffers), then
// branch-guard the col read (int64-indexed col read is OOB for int32 buffers!).

__global__ void k_front(const void* __restrict__ ei,
                        unsigned int* __restrict__ epack, unsigned short* __restrict__ dp,
                        const float* __restrict__ x, const float* __restrict__ W,
                        unsigned char* __restrict__ y0q, unsigned int* __restrict__ csr) {
    __shared__ __align__(16) unsigned char smem[SLICE_NODES * 4];  // 25 KB union
    if (blockIdx.x < CF_BLOCKS) {
        // ---- count: per (slice, chunk) LDS histogram -> dp[chunk][node] (u16) ----
        int* hist = (int*)smem;
        int slice = blockIdx.x & (N_SLICES - 1);
        int chunk = blockIdx.x >> 3;
        unsigned int lo = slice * SLICE_NODES;
        for (int i = threadIdx.x; i < SLICE_NODES; i += blockDim.x) hist[i] = 0;
        __syncthreads();
        int e0 = chunk * EPC;
        for (int k = 0; k < EPC / 256; ++k) {
            int e = e0 + k * 256 + threadIdx.x;
            long long v = ((const long long*)ei)[e];  // row half: in-bounds both dtypes
            bool bad = (v < 0 || v >= N_NODES);
            bool is32 = (__ballot(bad) != 0ull);  // wave-uniform
            unsigned int c;
            if (is32) {
                c = ((const unsigned int*)ei)[N_EDGES + e];
            } else {
                c = (unsigned int)((const long long*)ei)[N_EDGES + e];
            }
            if (c - lo < SLICE_NODES) atomicAdd(&hist[c - lo], 1);
        }
        __syncthreads();
        unsigned short* dpk = dp + (size_t)chunk * N_NODES + lo;
        for (int i = threadIdx.x; i < SLICE_NODES; i += blockDim.x)
            dpk[i] = (unsigned short)hist[i];
        return;
    }
    int rb = blockIdx.x - CF_BLOCKS;
    int super = rb >> 4;
    int pos = rb & 15;
    if (pos < 8) {
        int unit = super * 8 + pos;
        if (unit >= CONV_UNITS) return;
        int e = unit * 256 + threadIdx.x;
        long long v = __builtin_nontemporal_load((const long long*)ei + e);
        bool bad = (v < 0 || v >= N_NODES);
        bool is32 = (__ballot(bad) != 0ull);  // wave-uniform
        unsigned int r, c;
        if (is32) {
            const unsigned int* p = (const unsigned int*)ei;
            r = __builtin_nontemporal_load(p + e);
            c = __builtin_nontemporal_load(p + N_EDGES + e);
        } else {
            r = (unsigned int)v;
            c = (unsigned int)__builtin_nontemporal_load((const long long*)ei + N_EDGES + e);
        }
        epack[e] = r | (c << 16);
    } else if (pos < 13) {
        int unit = super * 5 + (pos - 8);
        if (unit >= LIN_UNITS) return;
        float4 (*Ws)[N_FEAT + 1] = (float4(*)[N_FEAT + 1])smem;  // 16.2 KB view
        for (int i = threadIdx.x; i < N_FEAT * (N_CLASSES / 4); i += blockDim.x) {
            int k = i / (N_CLASSES / 4), c4 = i - k * (N_CLASSES / 4);
            Ws[c4][k] = ((const float4*)W)[i];
        }
        __syncthreads();
        int idx = unit * 256 + threadIdx.x;
        if (idx >= N_NODES * (N_CLASSES / 4)) return;
        int n = idx / (N_CLASSES / 4);
        int c4 = idx - n * (N_CLASSES / 4);
        const float* hr = x + (size_t)n * N_FEAT;
        float4 s = {0.f, 0.f, 0.f, 0.f};
#pragma unroll
        for (int k = 0; k < N_FEAT; ++k) {
            float hv = hr[k];
            float4 w = Ws[c4][k];
            s.x += hv * w.x; s.y += hv * w.y; s.z += hv * w.z; s.w += hv * w.w;
        }
        uchar4 q = make_uchar4(f2q(s.x), f2q(s.y), f2q(s.z), f2q(s.w));
        *(uchar4*)(y0q + (size_t)n * ROWB + c4 * 4) = q;
    } else {
        // zero csr (pads must read as w=0,r=0)
        int unit = super * 3 + (pos - 13);
        if (unit >= ZERO_UNITS) return;
        ((uint4*)csr)[unit * 256 + threadIdx.x] = make_uint4(0u, 0u, 0u, 0u);
    }
}

// ---------------- scan1: actual deg -> dinv; PADDED deg -> offsets ----------------

__global__ void k_scan1(unsigned short* __restrict__ dp, int* __restrict__ offs,
                        int* __restrict__ sums, float* __restrict__ dinv,
                        unsigned short* __restrict__ dinv16) {
    __shared__ int s[SCAN_BLK];
    int i = blockIdx.x * SCAN_BLK + threadIdx.x;
    int padded = 0;
    if (i < N_NODES) {
        int run = 0;
#pragma unroll 5
        for (int k = 0; k < N_CHUNKS; ++k) {
            unsigned short* p = dp + (size_t)k * N_NODES + i;
            int t = *p;
            *p = (unsigned short)run;  // chunk-exclusive prefix within node (fits u16)
            run += t;
        }
        float d = rsqrtf((float)run + 1.0f);  // +1 self-loop, from ACTUAL degree
        dinv[i] = d;
        dinv16[i] = __half_as_ushort(__float2half_rn(d));
        padded = (run + PAD - 1) & ~(PAD - 1);
    }
    s[threadIdx.x] = padded;
    __syncthreads();
    int v = s[threadIdx.x];
    for (int off = 1; off < SCAN_BLK; off <<= 1) {
        int t = (threadIdx.x >= off) ? s[threadIdx.x - off] : 0;
        __syncthreads();
        s[threadIdx.x] += t;
        __syncthreads();
    }
    if (i < N_NODES) offs[i] = s[threadIdx.x] - v;  // exclusive within block
    if (threadIdx.x == SCAN_BLK - 1) sums[blockIdx.x] = s[SCAN_BLK - 1];
}

// scan2 folded in: every block redundantly scans the 196 block sums in LDS
__global__ void k_scan3(int* __restrict__ offs, const int* __restrict__ sums) {
    __shared__ int sc[SCAN_BLK];
    __shared__ int orig[SCAN_BLK];
    int t = threadIdx.x;
    int v = (t < N_SCAN_BLKS) ? sums[t] : 0;
    sc[t] = v; orig[t] = v;
    __syncthreads();
    for (int off = 1; off < SCAN_BLK; off <<= 1) {
        int u = (t >= off) ? sc[t - off] : 0;
        __syncthreads();
        sc[t] += u;
        __syncthreads();
    }
    int base = sc[blockIdx.x] - orig[blockIdx.x];
    int i = blockIdx.x * SCAN_BLK + t;
    if (i < N_NODES) offs[i] += base;
    if (blockIdx.x == 0 && t == N_SCAN_BLKS - 1) offs[N_NODES] = sc[t];  // total padded
}

// ---------------- fill: counting-sort placement; pos base in LDS; 4 edges/load ----------------

__global__ void k_fill(const unsigned int* __restrict__ epack,
                       const unsigned short* __restrict__ dinv16,
                       const int* __restrict__ offs, const unsigned short* __restrict__ dp,
                       unsigned int* __restrict__ csr) {
    __shared__ int pos[SLICE_NODES];  // 25 KB
    int slice = blockIdx.x & (N_SLICES - 1);
    int chunk = blockIdx.x >> 3;
    unsigned int lo = slice * SLICE_NODES;
    const unsigned short* dpk = dp + (size_t)chunk * N_NODES + lo;
    const int* ofs = offs + lo;
    for (int i = threadIdx.x; i < SLICE_NODES; i += blockDim.x)
        pos[i] = ofs[i] + dpk[i];
    __syncthreads();
    int g0 = chunk * (EPC / 4), g1 = g0 + (EPC / 4);
    for (int g = g0 + threadIdx.x; g < g1; g += blockDim.x) {
        uint4 p4 = ((const uint4*)epack)[g];
#pragma unroll
        for (int j = 0; j < 4; ++j) {
            unsigned int p = (j == 0) ? p4.x : (j == 1) ? p4.y : (j == 2) ? p4.z : p4.w;
            unsigned int c = p >> 16;
            if (c - lo < SLICE_NODES) {
                unsigned int r = p & 0xffffu;
                int pp = atomicAdd(&pos[c - lo], 1);
                csr[pp] = r | ((unsigned int)dinv16[r] << 16);
            }
        }
    }
}

// ---------------- pull-gather: zero-padded segments; cached csr; 16-slot iterations ----------------

#define GPROC(Q, ACC)                                                            \
    {                                                                            \
        unsigned int q_ = (Q);                                                   \
        float vv_ = q2f(sl[(size_t)(q_ & 0xffffu) * ROWB]);                      \
        ACC += __half2float(__ushort_as_half((unsigned short)(q_ >> 16))) * vv_; \
    }

template <bool LSM, typename DstT, int DSTRIDE>
__global__ void k_gather(const int* __restrict__ offs, const unsigned int* __restrict__ csr,
                         const unsigned char* __restrict__ src, const float* __restrict__ dinv,
                         DstT* __restrict__ dst, const float* __restrict__ bias) {
    int wave = threadIdx.x >> 6;
    int lane = threadIdx.x & 63;
    int n = blockIdx.x * 4 + wave;
    if (n >= N_NODES) return;
    int s = offs[n], e = offs[n + 1];  // both PAD-aligned; pads are zero entries
    bool act = (lane < N_CLASSES);
    float dc = dinv[n];
    const unsigned char* sl = src + lane;
    float acc0 = 0.0f, acc1 = 0.0f, acc2 = 0.0f, acc3 = 0.0f;
    if (act) acc0 = dc * q2f(sl[(size_t)n * ROWB]);  // self term (dc applied again at end)
    int base = s;
    for (; base + 16 <= e; base += 16) {   // 4 csr loads issued together -> 16 src loads in flight
        uint4 a0 = *(const uint4*)(csr + base);
        uint4 a1 = *(const uint4*)(csr + base + 4);
        uint4 a2 = *(const uint4*)(csr + base + 8);
        uint4 a3 = *(const uint4*)(csr + base + 12);
        if (act) {
            GPROC(a0.x, acc0) GPROC(a0.y, acc1) GPROC(a0.z, acc2) GPROC(a0.w, acc3)
            GPROC(a1.x, acc0) GPROC(a1.y, acc1) GPROC(a1.z, acc2) GPROC(a1.w, acc3)
            GPROC(a2.x, acc0) GPROC(a2.y, acc1) GPROC(a2.z, acc2) GPROC(a2.w, acc3)
            GPROC(a3.x, acc0) GPROC(a3.y, acc1) GPROC(a3.z, acc2) GPROC(a3.w, acc3)
        }
    }
    if (base < e) {                        // remainder is exactly 8 (PAD = 8)
        uint4 a0 = *(const uint4*)(csr + base);
        uint4 a1 = *(const uint4*)(csr + base + 4);
        if (act) {
            GPROC(a0.x, acc0) GPROC(a0.y, acc1) GPROC(a0.z, acc2) GPROC(a0.w, acc3)
            GPROC(a1.x, acc0) GPROC(a1.y, acc1) GPROC(a1.z, acc2) GPROC(a1.w, acc3)
        }
    }
    float acc = dc * ((acc0 + acc1) + (acc2 + acc3));
    if (!LSM) {
        if (act) {
            if constexpr (sizeof(DstT) == 1)
                dst[(size_t)n * DSTRIDE + lane] = (DstT)f2q(acc);
            else
                dst[(size_t)n * DSTRIDE + lane] = (DstT)acc;
        }
    } else {
        float v = act ? acc + bias[lane] : -INFINITY;
        float m = v;
#pragma unroll
        for (int off = 32; off; off >>= 1) m = fmaxf(m, __shfl_xor(m, off));
        float ex = act ? __expf(v - m) : 0.0f;
        float ssum = ex;
#pragma unroll
        for (int off = 32; off; off >>= 1) ssum += __shfl_xor(ssum, off);
        float ls = logf(ssum);
        if (act) dst[(size_t)n * DSTRIDE + lane] = (DstT)(v - m - ls);
    }
}

// ---------------- launch ----------------

extern "C" void kernel_launch(void* const* d_in, const int* in_sizes, int n_in,
                              void* d_out, int out_size, void* d_ws, size_t ws_size,
                              hipStream_t stream) {
    const float* x = (const float*)d_in[0];
    const void* ei = d_in[1];                // [2, E], int32 or int64 (wave-local detect)
    const float* W = (const float*)d_in[2];  // [F, C]
    const float* b = (const float*)d_in[3];  // [C]
    float* z = (float*)d_out;                // [N, C]

    char* ws = (char*)d_ws;
    size_t o = 0;
    auto alloc = [&](size_t bytes) { char* p = ws + o; o += (bytes + 255) & ~(size_t)255; return p; };
    unsigned int*   epack  = (unsigned int*)alloc((size_t)N_EDGES * 4);
    unsigned short* dp     = (unsigned short*)alloc((size_t)N_CHUNKS * N_NODES * 2);  // 12.5 MB
    float*          dinv   = (float*)alloc(N_NODES * 4);
    unsigned short* dinv16 = (unsigned short*)alloc(N_NODES * 2);
    int*            offs   = (int*)alloc((N_NODES + 1) * 4);
    int*            sums   = (int*)alloc(SCAN_BLK * 4);
    unsigned int*   csr    = (unsigned int*)alloc((size_t)CSR_ALLOC_ENTRIES * 4);
    unsigned char*  y0q    = (unsigned char*)alloc((size_t)N_NODES * ROWB);
    unsigned char*  h1q    = (unsigned char*)alloc((size_t)N_NODES * ROWB);

    const int T = 256;

    // count (blocks 0..999, dispatched first) + convert + linear + csr-zero, one grid
    k_front<<<FRONT_BLOCKS, T, 0, stream>>>(ei, epack, dp, x, W, y0q, csr);

    // scan: dinv from actual deg; offsets from PADDED deg
    k_scan1<<<N_SCAN_BLKS, SCAN_BLK, 0, stream>>>(dp, offs, sums, dinv, dinv16);
    k_scan3<<<N_SCAN_BLKS, SCAN_BLK, 0, stream>>>(offs, sums);

    // counting-sort fill into zero-padded segments
    k_fill<<<CF_BLOCKS, T, 0, stream>>>(epack, dinv16, offs, dp, csr);

    // hop 1: h1q = fp8(A_hat @ y0q)
    k_gather<false, unsigned char, ROWB><<<N_NODES / 4, T, 0, stream>>>(offs, csr, y0q, dinv, h1q, b);
    // hop 2 + bias + log_softmax
    k_gather<true, float, N_CLASSES><<<N_NODES / 4, T, 0, stream>>>(offs, csr, h1q, dinv, z, b);
}

// Round 27
// 118.076 us; speedup vs baseline: 1.0639x; 1.0639x over previous
//
#include <hip/hip_runtime.h>
#include <hip/hip_fp16.h>
#include <hip/hip_fp8.h>
#include <math.h>

#define N_NODES 50000
#define N_EDGES 800000
#define N_FEAT 100
#define N_CLASSES 40
#define ROWB 64                    // fp8 row stride: 40 data + 24 pad = 1 cache line
#define N_SLICES 8
#define SLICE_NODES 6250           // N_NODES / N_SLICES
#define N_CHUNKS 125
#define EPC 6400                   // N_EDGES / N_CHUNKS
#define CF_BLOCKS (N_SLICES * N_CHUNKS)  // 1000
#define SCAN_BLK 256
#define N_SCAN_BLKS 196
#define PAD 8                      // csr segment padding granularity (zero entries)
// grid-union super-groups of 16: 8 convert + 5 linear + 3 csr-zero
#define CONV_UNITS 3125
#define LIN_UNITS 1954
#define ZERO_UNITS 1173            // x256 uint4 = 1,201,152 entries >= max padded csr
#define N_SUPER 391
#define CL_BLOCKS (N_SUPER * 16)   // 6256
#define CSR_ALLOC_ENTRIES (ZERO_UNITS * 256 * 4)  // 1,201,152

// ---------------- fp8 e4m3 helpers ----------------

__device__ __forceinline__ unsigned char f2q(float x) {
    __hip_fp8_e4m3 q(x);
    return (unsigned char)q.__x;
}
#if __has_builtin(__builtin_amdgcn_cvt_f32_fp8)
__device__ __forceinline__ float q2f(unsigned int b) {
    return __builtin_amdgcn_cvt_f32_fp8((int)b, 0);
}
#else
__device__ __forceinline__ float q2f(unsigned int b) {
    __hip_fp8_e4m3 q;
    q.__x = (__hip_fp8_storage_t)(b & 0xffu);
    return (float)q;
}
#endif

// ---------------- grid-union: convert (8) + linear (5) + csr-zero (3) per 16-super ----------------

__global__ void k_conv_lin(const void* __restrict__ ei,
                           unsigned int* __restrict__ epack,
                           const float* __restrict__ x, const float* __restrict__ W,
                           unsigned char* __restrict__ y0q, unsigned int* __restrict__ csr) {
    __shared__ float4 Ws[N_CLASSES / 4][N_FEAT + 1];  // linear branch only
    int super = blockIdx.x >> 4;
    int pos = blockIdx.x & 15;
    if (pos < 8) {
        int unit = super * 8 + pos;
        if (unit >= CONV_UNITS) return;
        int e = unit * 256 + threadIdx.x;
        long long v = __builtin_nontemporal_load((const long long*)ei + e);
        bool bad = (v < 0 || v >= N_NODES);
        bool is32 = (__ballot(bad) != 0ull);  // wave-uniform
        unsigned int r, c;
        if (is32) {
            const unsigned int* p = (const unsigned int*)ei;
            r = __builtin_nontemporal_load(p + e);
            c = __builtin_nontemporal_load(p + N_EDGES + e);
        } else {
            r = (unsigned int)v;
            c = (unsigned int)__builtin_nontemporal_load((const long long*)ei + N_EDGES + e);
        }
        epack[e] = r | (c << 16);
    } else if (pos < 13) {
        int unit = super * 5 + (pos - 8);
        if (unit >= LIN_UNITS) return;
        for (int i = threadIdx.x; i < N_FEAT * (N_CLASSES / 4); i += blockDim.x) {
            int k = i / (N_CLASSES / 4), c4 = i - k * (N_CLASSES / 4);
            Ws[c4][k] = ((const float4*)W)[i];
        }
        __syncthreads();
        int idx = unit * 256 + threadIdx.x;
        if (idx >= N_NODES * (N_CLASSES / 4)) return;
        int n = idx / (N_CLASSES / 4);
        int c4 = idx - n * (N_CLASSES / 4);
        const float* hr = x + (size_t)n * N_FEAT;
        float4 s = {0.f, 0.f, 0.f, 0.f};
#pragma unroll
        for (int k = 0; k < N_FEAT; ++k) {
            float hv = hr[k];
            float4 w = Ws[c4][k];
            s.x += hv * w.x; s.y += hv * w.y; s.z += hv * w.z; s.w += hv * w.w;
        }
        uchar4 q = make_uchar4(f2q(s.x), f2q(s.y), f2q(s.z), f2q(s.w));
        *(uchar4*)(y0q + (size_t)n * ROWB + c4 * 4) = q;
    } else {
        // zero csr (pads must read as w=0,r=0)
        int unit = super * 3 + (pos - 13);
        if (unit >= ZERO_UNITS) return;
        ((uint4*)csr)[unit * 256 + threadIdx.x] = make_uint4(0u, 0u, 0u, 0u);
    }
}

// ---------------- count: per (slice, chunk) LDS histogram -> dp[chunk][node] (u16) ----------------

__global__ void k_count(const unsigned int* __restrict__ epack, unsigned short* __restrict__ dp) {
    __shared__ int hist[SLICE_NODES];  // 25 KB
    int slice = blockIdx.x & (N_SLICES - 1);
    int chunk = blockIdx.x >> 3;
    unsigned int lo = slice * SLICE_NODES;
    for (int i = threadIdx.x; i < SLICE_NODES; i += blockDim.x) hist[i] = 0;
    __syncthreads();
    int g0 = chunk * (EPC / 4), g1 = g0 + (EPC / 4);
    for (int g = g0 + threadIdx.x; g < g1; g += blockDim.x) {
        uint4 p4 = ((const uint4*)epack)[g];
        unsigned int c0 = p4.x >> 16, c1 = p4.y >> 16, c2 = p4.z >> 16, c3 = p4.w >> 16;
        if (c0 - lo < SLICE_NODES) atomicAdd(&hist[c0 - lo], 1);
        if (c1 - lo < SLICE_NODES) atomicAdd(&hist[c1 - lo], 1);
        if (c2 - lo < SLICE_NODES) atomicAdd(&hist[c2 - lo], 1);
        if (c3 - lo < SLICE_NODES) atomicAdd(&hist[c3 - lo], 1);
    }
    __syncthreads();
    unsigned short* dpk = dp + (size_t)chunk * N_NODES + lo;
    for (int i = threadIdx.x; i < SLICE_NODES; i += blockDim.x) dpk[i] = (unsigned short)hist[i];
}

// ---------------- scan1: actual deg -> dinv; PADDED deg -> offsets ----------------

__global__ void k_scan1(unsigned short* __restrict__ dp, int* __restrict__ offs,
                        int* __restrict__ sums, float* __restrict__ dinv,
                        unsigned short* __restrict__ dinv16) {
    __shared__ int s[SCAN_BLK];
    int i = blockIdx.x * SCAN_BLK + threadIdx.x;
    int padded = 0;
    if (i < N_NODES) {
        int run = 0;
#pragma unroll 5
        for (int k = 0; k < N_CHUNKS; ++k) {
            unsigned short* p = dp + (size_t)k * N_NODES + i;
            int t = *p;
            *p = (unsigned short)run;  // chunk-exclusive prefix within node (fits u16)
            run += t;
        }
        float d = rsqrtf((float)run + 1.0f);  // +1 self-loop, from ACTUAL degree
        dinv[i] = d;
        dinv16[i] = __half_as_ushort(__float2half_rn(d));
        padded = (run + PAD - 1) & ~(PAD - 1);
    }
    s[threadIdx.x] = padded;
    __syncthreads();
    int v = s[threadIdx.x];
    for (int off = 1; off < SCAN_BLK; off <<= 1) {
        int t = (threadIdx.x >= off) ? s[threadIdx.x - off] : 0;
        __syncthreads();
        s[threadIdx.x] += t;
        __syncthreads();
    }
    if (i < N_NODES) offs[i] = s[threadIdx.x] - v;  // exclusive within block
    if (threadIdx.x == SCAN_BLK - 1) sums[blockIdx.x] = s[SCAN_BLK - 1];
}

// scan2 folded in: every block redundantly scans the 196 block sums in LDS
__global__ void k_scan3(int* __restrict__ offs, const int* __restrict__ sums) {
    __shared__ int sc[SCAN_BLK];
    __shared__ int orig[SCAN_BLK];
    int t = threadIdx.x;
    int v = (t < N_SCAN_BLKS) ? sums[t] : 0;
    sc[t] = v; orig[t] = v;
    __syncthreads();
    for (int off = 1; off < SCAN_BLK; off <<= 1) {
        int u = (t >= off) ? sc[t - off] : 0;
        __syncthreads();
        sc[t] += u;
        __syncthreads();
    }
    int base = sc[blockIdx.x] - orig[blockIdx.x];
    int i = blockIdx.x * SCAN_BLK + t;
    if (i < N_NODES) offs[i] += base;
    if (blockIdx.x == 0 && t == N_SCAN_BLKS - 1) offs[N_NODES] = sc[t];  // total padded
}

// ---------------- fill: counting-sort placement; pos base in LDS; 4 edges/load ----------------

__global__ void k_fill(const unsigned int* __restrict__ epack,
                       const unsigned short* __restrict__ dinv16,
                       const int* __restrict__ offs, const unsigned short* __restrict__ dp,
                       unsigned int* __restrict__ csr) {
    __shared__ int pos[SLICE_NODES];  // 25 KB
    int slice = blockIdx.x & (N_SLICES - 1);
    int chunk = blockIdx.x >> 3;
    unsigned int lo = slice * SLICE_NODES;
    const unsigned short* dpk = dp + (size_t)chunk * N_NODES + lo;
    const int* ofs = offs + lo;
    for (int i = threadIdx.x; i < SLICE_NODES; i += blockDim.x)
        pos[i] = ofs[i] + dpk[i];
    __syncthreads();
    int g0 = chunk * (EPC / 4), g1 = g0 + (EPC / 4);
    for (int g = g0 + threadIdx.x; g < g1; g += blockDim.x) {
        uint4 p4 = ((const uint4*)epack)[g];
#pragma unroll
        for (int j = 0; j < 4; ++j) {
            unsigned int p = (j == 0) ? p4.x : (j == 1) ? p4.y : (j == 2) ? p4.z : p4.w;
            unsigned int c = p >> 16;
            if (c - lo < SLICE_NODES) {
                unsigned int r = p & 0xffffu;
                int pp = atomicAdd(&pos[c - lo], 1);
                csr[pp] = r | ((unsigned int)dinv16[r] << 16);
            }
        }
    }
}

// ---------------- pull-gather: zero-padded segments; cached csr; 16-slot iterations ----------------

#define GPROC(Q, ACC)                                                            \
    {                                                                            \
        unsigned int q_ = (Q);                                                   \
        float vv_ = q2f(sl[(size_t)(q_ & 0xffffu) * ROWB]);                      \
        ACC += __half2float(__ushort_as_half((unsigned short)(q_ >> 16))) * vv_; \
    }

template <bool LSM, typename DstT, int DSTRIDE>
__global__ void k_gather(const int* __restrict__ offs, const unsigned int* __restrict__ csr,
                         const unsigned char* __restrict__ src, const float* __restrict__ dinv,
                         DstT* __restrict__ dst, const float* __restrict__ bias) {
    int wave = threadIdx.x >> 6;
    int lane = threadIdx.x & 63;
    int n = blockIdx.x * 4 + wave;
    if (n >= N_NODES) return;
    int s = offs[n], e = offs[n + 1];  // both PAD-aligned; pads are zero entries
    bool act = (lane < N_CLASSES);
    float dc = dinv[n];
    const unsigned char* sl = src + lane;
    float acc0 = 0.0f, acc1 = 0.0f, acc2 = 0.0f, acc3 = 0.0f;
    if (act) acc0 = dc * q2f(sl[(size_t)n * ROWB]);  // self term (dc applied again at end)
    int base = s;
    for (; base + 16 <= e; base += 16) {   // 4 csr loads issued together -> 16 src loads in flight
        uint4 a0 = *(const uint4*)(csr + base);
        uint4 a1 = *(const uint4*)(csr + base + 4);
        uint4 a2 = *(const uint4*)(csr + base + 8);
        uint4 a3 = *(const uint4*)(csr + base + 12);
        if (act) {
            GPROC(a0.x, acc0) GPROC(a0.y, acc1) GPROC(a0.z, acc2) GPROC(a0.w, acc3)
            GPROC(a1.x, acc0) GPROC(a1.y, acc1) GPROC(a1.z, acc2) GPROC(a1.w, acc3)
            GPROC(a2.x, acc0) GPROC(a2.y, acc1) GPROC(a2.z, acc2) GPROC(a2.w, acc3)
            GPROC(a3.x, acc0) GPROC(a3.y, acc1) GPROC(a3.z, acc2) GPROC(a3.w, acc3)
        }
    }
    if (base < e) {                        // remainder is exactly 8 (PAD = 8)
        uint4 a0 = *(const uint4*)(csr + base);
        uint4 a1 = *(const uint4*)(csr + base + 4);
        if (act) {
            GPROC(a0.x, acc0) GPROC(a0.y, acc1) GPROC(a0.z, acc2) GPROC(a0.w, acc3)
            GPROC(a1.x, acc0) GPROC(a1.y, acc1) GPROC(a1.z, acc2) GPROC(a1.w, acc3)
        }
    }
    float acc = dc * ((acc0 + acc1) + (acc2 + acc3));
    if (!LSM) {
        if (act) {
            if constexpr (sizeof(DstT) == 1)
                dst[(size_t)n * DSTRIDE + lane] = (DstT)f2q(acc);
            else
                dst[(size_t)n * DSTRIDE + lane] = (DstT)acc;
        }
    } else {
        float v = act ? acc + bias[lane] : -INFINITY;
        float m = v;
#pragma unroll
        for (int off = 32; off; off >>= 1) m = fmaxf(m, __shfl_xor(m, off));
        float ex = act ? __expf(v - m) : 0.0f;
        float ssum = ex;
#pragma unroll
        for (int off = 32; off; off >>= 1) ssum += __shfl_xor(ssum, off);
        float ls = logf(ssum);
        if (act) dst[(size_t)n * DSTRIDE + lane] = (DstT)(v - m - ls);
    }
}

// ---------------- launch ----------------

extern "C" void kernel_launch(void* const* d_in, const int* in_sizes, int n_in,
                              void* d_out, int out_size, void* d_ws, size_t ws_size,
                              hipStream_t stream) {
    const float* x = (const float*)d_in[0];
    const void* ei = d_in[1];                // [2, E], int32 or int64 (wave-local detect)
    const float* W = (const float*)d_in[2];  // [F, C]
    const float* b = (const float*)d_in[3];  // [C]
    float* z = (float*)d_out;                // [N, C]

    char* ws = (char*)d_ws;
    size_t o = 0;
    auto alloc = [&](size_t bytes) { char* p = ws + o; o += (bytes + 255) & ~(size_t)255; return p; };
    unsigned int*   epack  = (unsigned int*)alloc((size_t)N_EDGES * 4);
    unsigned short* dp     = (unsigned short*)alloc((size_t)N_CHUNKS * N_NODES * 2);  // 12.5 MB
    float*          dinv   = (float*)alloc(N_NODES * 4);
    unsigned short* dinv16 = (unsigned short*)alloc(N_NODES * 2);
    int*            offs   = (int*)alloc((N_NODES + 1) * 4);
    int*            sums   = (int*)alloc(SCAN_BLK * 4);
    unsigned int*   csr    = (unsigned int*)alloc((size_t)CSR_ALLOC_ENTRIES * 4);
    unsigned char*  y0q    = (unsigned char*)alloc((size_t)N_NODES * ROWB);
    unsigned char*  h1q    = (unsigned char*)alloc((size_t)N_NODES * ROWB);

    const int T = 256;

    // convert + linear + csr-zero (all independent, one grid)
    k_conv_lin<<<CL_BLOCKS, T, 0, stream>>>(ei, epack, x, W, y0q, csr);

    // per-(slice,chunk) histogram -> dp (u16)
    k_count<<<CF_BLOCKS, T, 0, stream>>>(epack, dp);

    // scan: dinv from actual deg; offsets from PADDED deg
    k_scan1<<<N_SCAN_BLKS, SCAN_BLK, 0, stream>>>(dp, offs, sums, dinv, dinv16);
    k_scan3<<<N_SCAN_BLKS, SCAN_BLK, 0, stream>>>(offs, sums);

    // counting-sort fill into zero-padded segments
    k_fill<<<CF_BLOCKS, T, 0, stream>>>(epack, dinv16, offs, dp, csr);

    // hop 1: h1q = fp8(A_hat @ y0q)
    k_gather<false, unsigned char, ROWB><<<N_NODES / 4, T, 0, stream>>>(offs, csr, y0q, dinv, h1q, b);
    // hop 2 + bias + log_softmax
    k_gather<true, float, N_CLASSES><<<N_NODES / 4, T, 0, stream>>>(offs, csr, h1q, dinv, z, b);
}